// Round 2
// baseline (1414.292 us; speedup 1.0000x reference)
//
#include <hip/hip_runtime.h>
#include <stdint.h>

constexpr int BATCH = 16;
constexpr int LQ = 2048;
constexpr int LK = 2048;
constexpr int DQ = 1024;
constexpr int DK = 1024;
constexpr int DV = 1024;
constexpr float SCALE = 0.03125f;  // 1/sqrt(1024)

typedef __bf16 bf16x8 __attribute__((ext_vector_type(8)));
typedef float f32x4 __attribute__((ext_vector_type(4)));

__device__ __forceinline__ uint16_t f2bf(float x) {
  union { float f; uint32_t u; } v; v.f = x;
  uint32_t r = v.u + 0x7FFFu + ((v.u >> 16) & 1u);  // RNE
  return (uint16_t)(r >> 16);
}

// ---- stage a 128x32 fp32 tile -> LDS bf16 [row][k], 256 threads ----
__device__ __forceinline__ void stage_f32(const float* __restrict__ g, int ld,
                                          uint16_t* __restrict__ lds, int t) {
#pragma unroll
  for (int i = 0; i < 4; ++i) {
    int c = i * 256 + t;         // 1024 chunks of 4 floats
    int row = c >> 3;
    int col = (c & 7) << 2;
    float4 f = *(const float4*)(g + (size_t)row * ld + col);
    ushort4 h;
    h.x = f2bf(f.x); h.y = f2bf(f.y); h.z = f2bf(f.z); h.w = f2bf(f.w);
    *(ushort4*)(lds + row * 32 + col) = h;
  }
}

// ---- stage a 128x32 bf16 tile -> LDS [row][k], 256 threads ----
__device__ __forceinline__ void stage_bf16(const uint16_t* __restrict__ g, int ld,
                                           uint16_t* __restrict__ lds, int t) {
#pragma unroll
  for (int i = 0; i < 2; ++i) {
    int c = i * 256 + t;         // 512 chunks of 8 bf16 (16B)
    int row = c >> 2;
    int col = (c & 3) << 3;
    uint4 u = *(const uint4*)(g + (size_t)row * ld + col);
    *(uint4*)(lds + row * 32 + col) = u;
  }
}

// ---- stage a 32(k) x 128(n) fp32 tile (natural layout, ld = row stride)
//      -> LDS bf16 [n][k] (transposed), 256 threads ----
__device__ __forceinline__ void stage_f32_T(const float* __restrict__ g, int ld,
                                            uint16_t* __restrict__ lds, int t) {
  const int rp = t & 15;          // k-pair index: k = 2*rp, 2*rp+1
  const int c0 = (t >> 4) * 8;    // column group of 8
  const float* r0 = g + (size_t)(2 * rp) * ld + c0;
  const float* r1 = r0 + ld;
  float4 a0 = *(const float4*)(r0);
  float4 a1 = *(const float4*)(r0 + 4);
  float4 b0 = *(const float4*)(r1);
  float4 b1 = *(const float4*)(r1 + 4);
  float lo[8] = {a0.x, a0.y, a0.z, a0.w, a1.x, a1.y, a1.z, a1.w};
  float hi[8] = {b0.x, b0.y, b0.z, b0.w, b1.x, b1.y, b1.z, b1.w};
  uint32_t* w = (uint32_t*)lds;
#pragma unroll
  for (int j = 0; j < 8; ++j) {
    // LDS element (n = c0+j, k = 2rp) = lo, (k = 2rp+1) = hi, packed as one b32
    uint32_t val = (uint32_t)f2bf(lo[j]) | ((uint32_t)f2bf(hi[j]) << 16);
    w[(c0 + j) * 16 + rp] = val;   // 4-way bank conflict, small share of tile cost
  }
}

// ---- GEMM core: C[m][n] = sum_k A[m][k]*B'[n][k], 128x128 tile, BK=32 ----
// AMODE: 0 = bf16 k-contiguous, 1 = f32 k-contiguous
// BMODE: 0 = bf16 k-contiguous (B^T layout), 1 = f32 k-contiguous, 2 = f32 natural [k][n]
template <int AMODE, int BMODE>
__device__ __forceinline__ void gemm_core(const void* __restrict__ Ap, int lda,
                                          const void* __restrict__ Bp, int ldb,
                                          int K, uint16_t* As, uint16_t* Bs,
                                          f32x4 acc[4][4]) {
  const int t = threadIdx.x;
  const int lane = t & 63;
  const int wave = t >> 6;
  const int wm = (wave >> 1) * 64;
  const int wn = (wave & 1) * 64;
  const int fr = lane & 15;
  const int fk = (lane >> 4) * 8;
  for (int k0 = 0; k0 < K; k0 += 32) {
    if (AMODE == 1) stage_f32((const float*)Ap + k0, lda, As, t);
    else            stage_bf16((const uint16_t*)Ap + k0, lda, As, t);
    if (BMODE == 1)      stage_f32((const float*)Bp + k0, ldb, Bs, t);
    else if (BMODE == 0) stage_bf16((const uint16_t*)Bp + k0, ldb, Bs, t);
    else                 stage_f32_T((const float*)Bp + (size_t)k0 * ldb, ldb, Bs, t);
    __syncthreads();
    bf16x8 a[4], b[4];
#pragma unroll
    for (int i = 0; i < 4; ++i) {
      a[i] = *(const bf16x8*)(As + (wm + i * 16 + fr) * 32 + fk);
      b[i] = *(const bf16x8*)(Bs + (wn + i * 16 + fr) * 32 + fk);
    }
#pragma unroll
    for (int mi = 0; mi < 4; ++mi)
#pragma unroll
      for (int ni = 0; ni < 4; ++ni)
        acc[mi][ni] = __builtin_amdgcn_mfma_f32_16x16x32_bf16(a[mi], b[ni], acc[mi][ni], 0, 0, 0);
    __syncthreads();
  }
}

// ---- GEMM1: KT[m][n] = bf16(tanh(sum_d K[m][d]*W[n][d])), M=32768,N=1024,K=1024 ----
__global__ __launch_bounds__(256) void gemm_tanh_kernel(const float* __restrict__ Kin,
                                                        const float* __restrict__ W,
                                                        uint16_t* __restrict__ KT) {
  __shared__ __align__(16) uint16_t As[128 * 32];
  __shared__ __align__(16) uint16_t Bs[128 * 32];
  const int m0 = blockIdx.y * 128;
  const int n0 = blockIdx.x * 128;
  f32x4 acc[4][4];
#pragma unroll
  for (int i = 0; i < 4; ++i)
#pragma unroll
    for (int j = 0; j < 4; ++j) acc[i][j] = f32x4{0.f, 0.f, 0.f, 0.f};
  gemm_core<1, 1>(Kin + (size_t)m0 * DK, DK, W + (size_t)n0 * DK, DK, DK, As, Bs, acc);
  const int lane = threadIdx.x & 63;
  const int wave = threadIdx.x >> 6;
  const int gm = m0 + (wave >> 1) * 64 + (lane >> 4) * 4;
  const int gn = n0 + (wave & 1) * 64 + (lane & 15);
#pragma unroll
  for (int mi = 0; mi < 4; ++mi)
#pragma unroll
    for (int ni = 0; ni < 4; ++ni)
#pragma unroll
      for (int r = 0; r < 4; ++r)
        KT[(size_t)(gm + mi * 16 + r) * DQ + (gn + ni * 16)] = f2bf(tanhf(acc[mi][ni][r]));
}

// ---- GEMM2: S[b][m][n] = SCALE * sum_d q[b][m][d]*KT[b][n][d] ----
__global__ __launch_bounds__(256) void gemm_score_kernel(const float* __restrict__ q,
                                                         const uint16_t* __restrict__ KT,
                                                         float* __restrict__ S) {
  __shared__ __align__(16) uint16_t As[128 * 32];
  __shared__ __align__(16) uint16_t Bs[128 * 32];
  const int b = blockIdx.z;
  const int m0 = blockIdx.y * 128;
  const int n0 = blockIdx.x * 128;
  const float* A = q + (size_t)b * LQ * DQ + (size_t)m0 * DQ;
  const uint16_t* Bm = KT + (size_t)b * LK * DQ + (size_t)n0 * DQ;
  float* C = S + (size_t)b * LQ * LK;
  f32x4 acc[4][4];
#pragma unroll
  for (int i = 0; i < 4; ++i)
#pragma unroll
    for (int j = 0; j < 4; ++j) acc[i][j] = f32x4{0.f, 0.f, 0.f, 0.f};
  gemm_core<1, 0>(A, DQ, Bm, DQ, DQ, As, Bs, acc);
  const int lane = threadIdx.x & 63;
  const int wave = threadIdx.x >> 6;
  const int gm = m0 + (wave >> 1) * 64 + (lane >> 4) * 4;
  const int gn = n0 + (wave & 1) * 64 + (lane & 15);
#pragma unroll
  for (int mi = 0; mi < 4; ++mi)
#pragma unroll
    for (int ni = 0; ni < 4; ++ni)
#pragma unroll
      for (int r = 0; r < 4; ++r)
        C[(size_t)(gm + mi * 16 + r) * LK + (gn + ni * 16)] = acc[mi][ni][r] * SCALE;
}

// ---- GEMM3: out[b][m][n] = sum_j att[b][m][j]*v[b][j][n]  (v natural layout) ----
__global__ __launch_bounds__(256) void gemm_pv_kernel(const float* __restrict__ att,
                                                      const float* __restrict__ v,
                                                      float* __restrict__ out) {
  __shared__ __align__(16) uint16_t As[128 * 32];
  __shared__ __align__(16) uint16_t Bs[128 * 32];
  const int b = blockIdx.z;
  const int m0 = blockIdx.y * 128;
  const int n0 = blockIdx.x * 128;
  const float* A = att + (size_t)b * LQ * LK + (size_t)m0 * LK;
  const float* Bm = v + (size_t)b * LK * DV + n0;  // (k=0, n=n0); k advances by ldb
  float* C = out + (size_t)b * LQ * DV;
  f32x4 acc[4][4];
#pragma unroll
  for (int i = 0; i < 4; ++i)
#pragma unroll
    for (int j = 0; j < 4; ++j) acc[i][j] = f32x4{0.f, 0.f, 0.f, 0.f};
  gemm_core<1, 2>(A, LK, Bm, DV, LK, As, Bs, acc);
  const int lane = threadIdx.x & 63;
  const int wave = threadIdx.x >> 6;
  const int gm = m0 + (wave >> 1) * 64 + (lane >> 4) * 4;
  const int gn = n0 + (wave & 1) * 64 + (lane & 15);
#pragma unroll
  for (int mi = 0; mi < 4; ++mi)
#pragma unroll
    for (int ni = 0; ni < 4; ++ni)
#pragma unroll
      for (int r = 0; r < 4; ++r)
        C[(size_t)(gm + mi * 16 + r) * DV + (gn + ni * 16)] = acc[mi][ni][r];
}

// ---- masked row softmax in place: att row of 2048, masked cols -> 0 ----
__global__ __launch_bounds__(256) void softmax_kernel(float* __restrict__ att,
                                                      const int* __restrict__ kidx) {
  const int row = blockIdx.x;       // 0..B*LQ-1
  const int b = row >> 11;          // /2048
  float* p = att + (size_t)row * LK;
  const int* idx = kidx + (size_t)b * LK;
  const int t = threadIdx.x;
  float v[8];
#pragma unroll
  for (int i = 0; i < 8; ++i) {
    const int j = i * 256 + t;
    float s = p[j];
    v[i] = (idx[j] == 0) ? -__builtin_inff() : s;
  }
  float mx = v[0];
#pragma unroll
  for (int i = 1; i < 8; ++i) mx = fmaxf(mx, v[i]);
#pragma unroll
  for (int o = 32; o > 0; o >>= 1) mx = fmaxf(mx, __shfl_xor(mx, o, 64));
  __shared__ float redm[4];
  __shared__ float reds[4];
  const int wave = t >> 6, lane = t & 63;
  if (lane == 0) redm[wave] = mx;
  __syncthreads();
  mx = fmaxf(fmaxf(redm[0], redm[1]), fmaxf(redm[2], redm[3]));
  float sum = 0.f;
#pragma unroll
  for (int i = 0; i < 8; ++i) {
    v[i] = __expf(v[i] - mx);   // masked: exp(-inf)=0 -> att exactly 0 (matches ref underflow)
    sum += v[i];
  }
#pragma unroll
  for (int o = 32; o > 0; o >>= 1) sum += __shfl_xor(sum, o, 64);
  if (lane == 0) reds[wave] = sum;
  __syncthreads();
  sum = reds[0] + reds[1] + reds[2] + reds[3];
  const float inv = 1.0f / sum;
#pragma unroll
  for (int i = 0; i < 8; ++i) p[i * 256 + t] = v[i] * inv;
}

extern "C" void kernel_launch(void* const* d_in, const int* in_sizes, int n_in,
                              void* d_out, int out_size, void* d_ws, size_t ws_size,
                              hipStream_t stream) {
  const float* q = (const float*)d_in[0];
  const float* k = (const float*)d_in[1];
  const float* v = (const float*)d_in[2];
  const int* kidx = (const int*)d_in[3];
  const float* W = (const float*)d_in[4];

  float* out = (float*)d_out;                       // [16,2048,1024] fp32
  float* att = out + (size_t)BATCH * LQ * DV;       // [16,2048,2048] fp32
  // KT (bf16, 67MB) parked in the out region: dead before gemm_pv overwrites out.
  // NO d_ws usage — round-1 post-timing divergence traced to writing 67MB of vT
  // into d_ws without checking ws_size (OOB likely corrupted pristine inputs).
  uint16_t* KT = (uint16_t*)d_out;

  gemm_tanh_kernel<<<dim3(DQ / 128, (BATCH * LK) / 128), 256, 0, stream>>>(k, W, KT);
  gemm_score_kernel<<<dim3(LK / 128, LQ / 128, BATCH), 256, 0, stream>>>(q, KT, att);
  softmax_kernel<<<BATCH * LQ, 256, 0, stream>>>(att, kidx);
  gemm_pv_kernel<<<dim3(DV / 128, LQ / 128, BATCH), 256, 0, stream>>>(att, v, out);
}